// Round 1
// baseline (41.712 us; speedup 1.0000x reference)
//
#include <hip/hip_runtime.h>
#include <math.h>

// Problem constants (fixed by the reference):
//   inputs [B=1024, S=7, S=7, C=512] f32, NHWC -> channels contiguous.
//   k_pp = 10 (top-10 channels per pixel), k_c = 22 (top-22 of center pixel).
//   out[b][0:22]            = top-22 of pixel (3,3)
//   out[b][22 + p*10 + j]   = top-10 of pixel p (p = s1*7+s2), j sorted desc.
#define NPIX 49
#define C_CH 512
#define CENTER_PIX 24
#define K_PP 10
#define K_C 22
#define WAVES_PER_BLOCK 4

// Descending compare-exchange: v[i] keeps max, v[j] keeps min.
#define CE(i, j)                       \
    do {                               \
        float _a = v[i], _b = v[j];    \
        v[i] = fmaxf(_a, _b);          \
        v[j] = fminf(_a, _b);          \
    } while (0)

// Sort 8 elements descending — Batcher odd-even mergesort, 19 comparators.
__device__ __forceinline__ void sort8_desc(float (&v)[8]) {
    CE(0, 1); CE(2, 3); CE(4, 5); CE(6, 7);
    CE(0, 2); CE(1, 3); CE(4, 6); CE(5, 7);
    CE(1, 2); CE(5, 6);
    CE(0, 4); CE(1, 5); CE(2, 6); CE(3, 7);
    CE(2, 4); CE(3, 5);
    CE(1, 2); CE(3, 4); CE(5, 6);
}

// Extract the wave-wide top-K (descending). Each lane holds a descending
// 8-element list in registers; per round, wave-max of heads, the owning lane
// (lowest lane on ties) shifts its list down (all static indexing -> stays in
// VGPRs). Lane `it` records result `it`, so lanes 0..K-1 return sorted top-K.
template <int K>
__device__ __forceinline__ float topk_extract(float (&v)[8], int lane) {
    float res = 0.0f;
#pragma unroll
    for (int it = 0; it < K; ++it) {
        float m = v[0];
#pragma unroll
        for (int s = 1; s < 64; s <<= 1) m = fmaxf(m, __shfl_xor(m, s));
        unsigned long long msk = __ballot(v[0] == m);
        int owner = __ffsll(msk) - 1;
        if (lane == owner) {
#pragma unroll
            for (int i = 0; i < 7; ++i) v[i] = v[i + 1];
            v[7] = -INFINITY;
        }
        if (lane == it) res = m;
    }
    return res;
}

__global__ __launch_bounds__(WAVES_PER_BLOCK * 64) void
channel_topk_kernel(const float* __restrict__ in, float* __restrict__ out) {
    const int wave = blockIdx.x * WAVES_PER_BLOCK + (threadIdx.x >> 6);
    const int lane = threadIdx.x & 63;
    const int b = wave / NPIX;
    const int pix = wave - b * NPIX;

    const float* src = in + (size_t)wave * C_CH;
    // 512 channels / 64 lanes = 8 per lane, two coalesced float4 loads.
    const float4 va = *reinterpret_cast<const float4*>(src + lane * 4);
    const float4 vb = *reinterpret_cast<const float4*>(src + 256 + lane * 4);
    float v[8] = {va.x, va.y, va.z, va.w, vb.x, vb.y, vb.z, vb.w};

    sort8_desc(v);

    float* obase = out + (size_t)b * C_CH;
    if (pix == CENTER_PIX) {
        // Wave-uniform branch: center pixel needs top-22; its pixel slot's
        // top-10 is the first 10 of those.
        const float r = topk_extract<K_C>(v, lane);
        if (lane < K_C) obase[lane] = r;
        if (lane < K_PP) obase[K_C + CENTER_PIX * K_PP + lane] = r;
    } else {
        const float r = topk_extract<K_PP>(v, lane);
        if (lane < K_PP) obase[K_C + pix * K_PP + lane] = r;
    }
}

extern "C" void kernel_launch(void* const* d_in, const int* in_sizes, int n_in,
                              void* d_out, int out_size, void* d_ws, size_t ws_size,
                              hipStream_t stream) {
    const float* in = (const float*)d_in[0];
    float* out = (float*)d_out;
    const int B = 1024;
    const int total_waves = B * NPIX;                       // 50176
    const int blocks = total_waves / WAVES_PER_BLOCK;       // 12544
    channel_topk_kernel<<<blocks, WAVES_PER_BLOCK * 64, 0, stream>>>(in, out);
}

// Round 2
// 33.317 us; speedup vs baseline: 1.2520x; 1.2520x over previous
//
#include <hip/hip_runtime.h>
#include <math.h>

// Problem constants (fixed by the reference):
//   inputs [B=1024, S=7, S=7, C=512] f32, NHWC -> channels contiguous.
//   k_pp = 10 (top-10 channels per pixel), k_c = 22 (top-22 of center pixel).
//   out[b][0:22]            = top-22 of pixel (3,3)
//   out[b][22 + p*10 + j]   = top-10 of pixel p (p = s1*7+s2), j sorted desc.
#define NPIX 49
#define C_CH 512
#define CENTER_PIX 24
#define K_PP 10
#define K_C 22
#define WAVES_PER_BLOCK 4

// Descending compare-exchange: v[i] keeps max, v[j] keeps min.
#define CE(i, j)                       \
    do {                               \
        float _a = v[i], _b = v[j];    \
        v[i] = fmaxf(_a, _b);          \
        v[j] = fminf(_a, _b);          \
    } while (0)

// Sort 8 elements descending — Batcher odd-even mergesort, 19 comparators.
__device__ __forceinline__ void sort8_desc(float (&v)[8]) {
    CE(0, 1); CE(2, 3); CE(4, 5); CE(6, 7);
    CE(0, 2); CE(1, 3); CE(4, 6); CE(5, 7);
    CE(1, 2); CE(5, 6);
    CE(0, 4); CE(1, 5); CE(2, 6); CE(3, 7);
    CE(2, 4); CE(3, 5);
    CE(1, 2); CE(3, 4); CE(5, 6);
}

// One DPP max step: x = max(x, dpp_perm(x)). VALU-only (no LDS/DS pipe).
// bound_ctrl=false + old=own-value => invalid source lanes compute max(x,x).
template <int CTRL>
__device__ __forceinline__ float dpp_maxf(float x) {
    int xi = __float_as_int(x);
    int yi = __builtin_amdgcn_update_dpp(xi, xi, CTRL, 0xF, 0xF, false);
    return fmaxf(x, __int_as_float(yi));
}

// Full-wave (64-lane) max via the canonical GCN DPP reduction, result
// broadcast uniformly via readlane from lane 63. Zero DS-pipe traffic.
__device__ __forceinline__ float wave_max_uniform(float x) {
    x = dpp_maxf<0x111>(x);  // row_shr:1
    x = dpp_maxf<0x112>(x);  // row_shr:2
    x = dpp_maxf<0x114>(x);  // row_shr:4
    x = dpp_maxf<0x118>(x);  // row_shr:8  -> lane 15 of each row = row max
    x = dpp_maxf<0x142>(x);  // row_bcast15 -> lane 31 = max(0..31), 63 = max(32..63)
    x = dpp_maxf<0x143>(x);  // row_bcast31 -> lane 63 = max(0..63)
    return __int_as_float(__builtin_amdgcn_readlane(__float_as_int(x), 63));
}

// Extract the wave-wide top-K (descending). Each lane holds a descending
// 8-element list in registers; per round, DPP wave-max of heads, the owning
// lane (lowest lane on ties) shifts its list down via cndmask (all static
// indexing -> stays in VGPRs). Lane `it` records result `it`.
template <int K>
__device__ __forceinline__ float topk_extract(float (&v)[8], int lane) {
    float res = 0.0f;
#pragma unroll
    for (int it = 0; it < K; ++it) {
        const float m = wave_max_uniform(v[0]);
        const unsigned long long msk = __ballot(v[0] == m);
        const int owner = __ffsll(msk) - 1;
        const bool own = (lane == owner);
        v[0] = own ? v[1] : v[0];
        v[1] = own ? v[2] : v[1];
        v[2] = own ? v[3] : v[2];
        v[3] = own ? v[4] : v[3];
        v[4] = own ? v[5] : v[4];
        v[5] = own ? v[6] : v[5];
        v[6] = own ? v[7] : v[6];
        v[7] = own ? -INFINITY : v[7];
        if (lane == it) res = m;
    }
    return res;
}

__global__ __launch_bounds__(WAVES_PER_BLOCK * 64) void
channel_topk_kernel(const float* __restrict__ in, float* __restrict__ out) {
    const int wave = blockIdx.x * WAVES_PER_BLOCK + (threadIdx.x >> 6);
    const int lane = threadIdx.x & 63;
    const int b = wave / NPIX;
    const int pix = wave - b * NPIX;

    const float* src = in + (size_t)wave * C_CH;
    // 512 channels / 64 lanes = 8 per lane, two coalesced float4 loads.
    const float4 va = *reinterpret_cast<const float4*>(src + lane * 4);
    const float4 vb = *reinterpret_cast<const float4*>(src + 256 + lane * 4);
    float v[8] = {va.x, va.y, va.z, va.w, vb.x, vb.y, vb.z, vb.w};

    sort8_desc(v);

    float* obase = out + (size_t)b * C_CH;
    if (pix == CENTER_PIX) {
        // Wave-uniform branch: center pixel needs top-22; its pixel slot's
        // top-10 is the first 10 of those.
        const float r = topk_extract<K_C>(v, lane);
        if (lane < K_C) obase[lane] = r;
        if (lane < K_PP) obase[K_C + CENTER_PIX * K_PP + lane] = r;
    } else {
        const float r = topk_extract<K_PP>(v, lane);
        if (lane < K_PP) obase[K_C + pix * K_PP + lane] = r;
    }
}

extern "C" void kernel_launch(void* const* d_in, const int* in_sizes, int n_in,
                              void* d_out, int out_size, void* d_ws, size_t ws_size,
                              hipStream_t stream) {
    const float* in = (const float*)d_in[0];
    float* out = (float*)d_out;
    const int B = 1024;
    const int total_waves = B * NPIX;                       // 50176
    const int blocks = total_waves / WAVES_PER_BLOCK;       // 12544
    channel_topk_kernel<<<blocks, WAVES_PER_BLOCK * 64, 0, stream>>>(in, out);
}